// Round 4
// baseline (191.429 us; speedup 1.0000x reference)
//
#include <hip/hip_runtime.h>
#include <cstddef>

#define SEQLEN 32
#define BATCH  32768
#define POSE   34
#define PREDL  15

typedef __attribute__((ext_vector_type(8))) short short8;
typedef __attribute__((ext_vector_type(4))) float f32x4;
typedef union { short8 s8; unsigned u[4]; } pk8;

__device__ __forceinline__ float sigm(float x){ return __builtin_amdgcn_rcpf(1.0f+__expf(-x)); }
__device__ __forceinline__ float tanh_(float x){ return fmaf(2.0f, __builtin_amdgcn_rcpf(1.0f+__expf(-2.0f*x)), -1.0f); }
__device__ __forceinline__ unsigned short f2bf(float f){ __bf16 b=(__bf16)f; return __builtin_bit_cast(unsigned short,b); }
__device__ __forceinline__ unsigned f22bf(float lo,float hi){ return (unsigned)f2bf(lo) | ((unsigned)f2bf(hi)<<16); }

// ---- B-fragment builders (B[k][n]: col n = lane&15 = batch, k = 8*(lane>>4)+e) ----
// k-chunk layout [h0..h1 pairs at k=8..24 relative]: used for K=64 tail chunk
// (x32,x33 | bias@34 | h@40..56 | 0) AND for folded-crossing K=32 chunk
// (p0,p1 | bias@2 | hc@8..24 | 0) -- identical structure.
__device__ __forceinline__ short8 mk_b1(unsigned hp0,unsigned hp1,int lo,int g,unsigned u0g0){
    int sA=(lo+32*(g-1))&63, sB=(sA+16)&63;
    unsigned a=__shfl(hp0,sA,64), b=__shfl(hp1,sA,64);
    unsigned c=__shfl(hp0,sB,64), d=__shfl(hp1,sB,64);
    bool mid=(g==1)||(g==2);
    pk8 r;
    r.u[0]=(g==0)?u0g0:(mid?a:0u);
    r.u[1]=(g==0)?0x3F80u:(mid?b:0u);   // bf16(1.0) in low half (bias slot)
    r.u[2]=mid?c:0u;
    r.u[3]=mid?d:0u;
    return r.s8;
}
// K=32 chunk: [h dims 0..16 at k=0..16 | bias@16 | 0]  (mlp/fcc/fc heads + folded dec)
__device__ __forceinline__ short8 mk_bh(unsigned hp0,unsigned hp1,int lo,int g){
    int sA=(lo+32*g)&63, sB=(sA+16)&63;
    unsigned a=__shfl(hp0,sA,64), b=__shfl(hp1,sA,64);
    unsigned c=__shfl(hp0,sB,64), d=__shfl(hp1,sB,64);
    bool lowg=(g<2);
    pk8 r;
    r.u[0]=lowg?a:(g==2?0x3F80u:0u);
    r.u[1]=lowg?b:0u;
    r.u[2]=lowg?c:0u;
    r.u[3]=lowg?d:0u;
    return r.s8;
}
__device__ __forceinline__ short8 mk_bx(const float2 (&xp)[5]){
    pk8 r;
    r.u[0]=f22bf(xp[0].x,xp[0].y);
    r.u[1]=f22bf(xp[1].x,xp[1].y);
    r.u[2]=f22bf(xp[2].x,xp[2].y);
    r.u[3]=f22bf(xp[3].x,xp[3].y);
    return r.s8;
}
__device__ __forceinline__ void ldx(const float* __restrict__ obs, int t, int wb, int lo, int g,
                                    float2 (&xp)[5]){
    const float* rb = obs + ((size_t)t*BATCH + wb + lo)*POSE;
    const float2* p2 = (const float2*)(rb + 8*g);
    xp[0]=p2[0]; xp[1]=p2[1]; xp[2]=p2[2]; xp[3]=p2[3];
    xp[4]=*(const float2*)(rb+32);
}

__device__ __forceinline__ void gates8(const short8 (&w)[4][2], short8 b0, short8 b1, f32x4 acc[4]){
    const f32x4 z={0.f,0.f,0.f,0.f};
#pragma unroll
    for(int gt=0;gt<4;++gt){
        f32x4 c=__builtin_amdgcn_mfma_f32_16x16x32_bf16(w[gt][0],b0,z,0,0,0);
        acc[gt]=__builtin_amdgcn_mfma_f32_16x16x32_bf16(w[gt][1],b1,c,0,0,0);
    }
}
__device__ __forceinline__ void gates4(const short8 (&w)[4], short8 b, f32x4 acc[4]){
    const f32x4 z={0.f,0.f,0.f,0.f};
#pragma unroll
    for(int gt=0;gt<4;++gt)
        acc[gt]=__builtin_amdgcn_mfma_f32_16x16x32_bf16(w[gt],b,z,0,0,0);
}
__device__ __forceinline__ void cell_pointwise(const f32x4 acc[4], float cst[4], float hv[4]){
#pragma unroll
    for(int j=0;j<4;++j){
        float iv=sigm(acc[0][j]);
        float fv=sigm(acc[1][j]);
        float gv=tanh_(acc[2][j]);
        float ov=sigm(acc[3][j]);
        float cn=fmaf(fv,cst[j],iv*gv);
        cst[j]=cn;
        hv[j]=ov*tanh_(cn);
    }
}
// encoder step: D[gate-dim][batch]; per lane: dims 4g+j of batch lo
__device__ __forceinline__ void enc_step(const float* __restrict__ obs, int t, int wb, int lo, int g,
                                         const short8 (&wE)[4][2], float2 (&xp)[5],
                                         unsigned &hp0, unsigned &hp1, float (&cst)[4]){
    short8 b0=mk_bx(xp);
    short8 b1=mk_b1(hp0,hp1,lo,g, f22bf(xp[4].x,xp[4].y));
    if(t+2<SEQLEN && lo<8) ldx(obs,t+2,wb,lo,g,xp);
    f32x4 acc[4]; gates8(wE,b0,b1,acc);
    float hv[4]; cell_pointwise(acc,cst,hv);
    hp0=f22bf(hv[0],hv[1]); hp1=f22bf(hv[2],hv[3]);
}

// stage one cell's K=64 weights: [x:0..34 | bias@34 | pad | h:40..56 | 0]
__device__ __forceinline__ void stage_w(unsigned short (*Wt)[16][64],
                                        const float* __restrict__ Wih, const float* __restrict__ Whh,
                                        const float* __restrict__ bih, const float* __restrict__ bhh,
                                        int tid){
    for(int idx=tid; idx<4096; idx+=256){
        int k=idx&63, n=(idx>>6)&15, gt=idx>>10;
        int row=gt*16+n;
        float v=0.f;
        if(k<34) v=Wih[row*34+k];
        else if(k==34) v=bih[row]+bhh[row];
        else if(k>=40&&k<56) v=Whh[row*16+(k-40)];
        Wt[gt][n][k]=f2bf(v);
    }
}

extern "C" __global__ void __launch_bounds__(256,4) lstm_k(
    const float* __restrict__ obs_s,
    const float* __restrict__ eWih, const float* __restrict__ eWhh,
    const float* __restrict__ ebih, const float* __restrict__ ebhh,
    const float* __restrict__ dWih, const float* __restrict__ dWhh,
    const float* __restrict__ dbih, const float* __restrict__ dbhh,
    const float* __restrict__ cWih, const float* __restrict__ cWhh,
    const float* __restrict__ cbih, const float* __restrict__ cbhh,
    const float* __restrict__ fcW,  const float* __restrict__ fcb,
    const float* __restrict__ fccW, const float* __restrict__ fccb,
    const float* __restrict__ mlpW, const float* __restrict__ mlpb,
    const float* __restrict__ embW, const float* __restrict__ embb,
    float* __restrict__ out_s, float* __restrict__ out_cr)
{
    __shared__ unsigned short WtU[3][4][16][64];  // enc / dec(s0) / cr(s0)
    __shared__ unsigned short WpC[4][16][32];     // folded crossing: [Wih_c*embW | bias' | Whh_c]
    __shared__ unsigned short WdE[4][16][32];     // folded decoder:  [Wih_d*fcW + Whh_d | bias']
    __shared__ unsigned short fcT[3][16][32];     // fc head, k16=bias
    __shared__ unsigned short mlpT[16][32];
    __shared__ unsigned short fccT[16][32];
    __shared__ float2 pbuf[4][16];

    const int tid=threadIdx.x;
    const int lane=tid&63;
    const int wv=tid>>6;
    const int lo=lane&15;
    const int g=lane>>4;
    const int wb=blockIdx.x*32 + wv*8;

    // ---------------- one-time staging ----------------
    stage_w(WtU[0], eWih,eWhh,ebih,ebhh, tid);
    stage_w(WtU[1], dWih,dWhh,dbih,dbhh, tid);
    stage_w(WtU[2], cWih,cWhh,cbih,cbhh, tid);
    for(int idx=tid; idx<4*16*32; idx+=256){          // WpC
        int k=idx&31, n=(idx>>5)&15, gt=idx>>9;
        int row=gt*16+n;
        float v=0.f;
        if(k<2){ float s=0.f; for(int j=0;j<34;++j) s+=cWih[row*34+j]*embW[2*j+k]; v=s; }
        else if(k==2){ float s=cbih[row]+cbhh[row]; for(int j=0;j<34;++j) s+=cWih[row*34+j]*embb[j]; v=s; }
        else if(k>=8&&k<24) v=cWhh[row*16+(k-8)];
        WpC[gt][n][k]=f2bf(v);
    }
    for(int idx=tid; idx<4*16*32; idx+=256){          // WdE
        int k=idx&31, n=(idx>>5)&15, gt=idx>>9;
        int row=gt*16+n;
        float v=0.f;
        if(k<16){ float s=dWhh[row*16+k]; for(int p=0;p<34;++p) s+=dWih[row*34+p]*fcW[p*16+k]; v=s; }
        else if(k==16){ float s=dbih[row]+dbhh[row]; for(int p=0;p<34;++p) s+=dWih[row*34+p]*fcb[p]; v=s; }
        WdE[gt][n][k]=f2bf(v);
    }
    for(int idx=tid; idx<3*16*32; idx+=256){          // fc head
        int k=idx&31, n=(idx>>5)&15, nt=idx>>9;
        int np=nt*16+n;
        float v=0.f;
        if(np<34){ if(k<16) v=fcW[np*16+k]; else if(k==16) v=fcb[np]; }
        fcT[nt][n][k]=f2bf(v);
    }
    for(int idx=tid; idx<512; idx+=256){              // mlp + fcc heads
        int k=idx&31, n=idx>>5;
        mlpT[n][k]=f2bf(k<16 ? mlpW[n*16+k] : (k==16 ? mlpb[n] : 0.f));
        float v=0.f;
        if(n<2){ if(k<16) v=fccW[n*16+k]; else if(k==16) v=fccb[n]; }
        fccT[n][k]=f2bf(v);
    }
    __syncthreads();   // only barrier; waves independent afterwards

    // ---------------- encoder ----------------
    short8 wE[4][2];
#pragma unroll
    for(int gt=0;gt<4;++gt){
        wE[gt][0]=*(const short8*)&WtU[0][gt][lo][8*g];
        wE[gt][1]=*(const short8*)&WtU[0][gt][lo][32+8*g];
    }
    float cst[4]={0.f,0.f,0.f,0.f};
    unsigned hp0=0u, hp1=0u;
    float2 xpA[5]={}, xpB[5]={};
    if(lo<8){ ldx(obs_s,0,wb,lo,g,xpA); ldx(obs_s,1,wb,lo,g,xpB); }
    for(int tt=0;tt<16;++tt){
        enc_step(obs_s,2*tt,  wb,lo,g,wE,xpA,hp0,hp1,cst);
        enc_step(obs_s,2*tt+1,wb,lo,g,wE,xpB,hp0,hp1,cst);
    }

    // ---------------- decoder setup ----------------
    float2 xq[5]={};
    if(lo<8) ldx(obs_s,SEQLEN-1,wb,lo,g,xq);      // obs[-1]
    const f32x4 z4={0.f,0.f,0.f,0.f};
    short8 wM =*(const short8*)&mlpT[lo][8*g];
    short8 wFC=*(const short8*)&fccT[lo][8*g];
    short8 wF[3];
#pragma unroll
    for(int nt=0;nt<3;++nt) wF[nt]=*(const short8*)&fcT[nt][lo][8*g];
    short8 wCp[4], wDe[4];
#pragma unroll
    for(int gt=0;gt<4;++gt){
        wCp[gt]=*(const short8*)&WpC[gt][lo][8*g];
        wDe[gt]=*(const short8*)&WdE[gt][lo][8*g];
    }
    // hc = mlp(h_enc)
    short8 bhE=mk_bh(hp0,hp1,lo,g);
    f32x4 hca=__builtin_amdgcn_mfma_f32_16x16x32_bf16(wM,bhE,z4,0,0,0);
    unsigned hcp0=f22bf(hca[0],hca[1]), hcp1=f22bf(hca[2],hca[3]);
    float cc[4]={0.f,0.f,0.f,0.f};

#define DEC_TAIL(S)                                                            \
    {                                                                          \
        float hcv[4]; cell_pointwise(accc,cc,hcv);                             \
        hcp0=f22bf(hcv[0],hcv[1]); hcp1=f22bf(hcv[2],hcv[3]);                  \
        short8 bhc=mk_bh(hcp0,hcp1,lo,g);                                      \
        f32x4 zac=__builtin_amdgcn_mfma_f32_16x16x32_bf16(wFC,bhc,z4,0,0,0);   \
        if(g==0){                                                              \
            float z0=zac[0], z1=zac[1];                                        \
            float mx=fmaxf(z0,z1);                                             \
            float e0=__expf(z0-mx), e1=__expf(z1-mx);                          \
            float rs=__builtin_amdgcn_rcpf(e0+e1);                             \
            float2 p=make_float2(e0*rs,e1*rs);                                 \
            pbuf[wv][lo]=p;                                                    \
            if(lo<8) ((float2*)out_cr)[(size_t)(S)*BATCH+wb+lo]=p;             \
        }                                                                      \
        float hv[4]; cell_pointwise(accd,cst,hv);                              \
        hp0=f22bf(hv[0],hv[1]); hp1=f22bf(hv[2],hv[3]);                        \
        short8 bhd=mk_bh(hp0,hp1,lo,g);                                        \
        f32x4 o0=__builtin_amdgcn_mfma_f32_16x16x32_bf16(wF[0],bhd,z4,0,0,0);  \
        f32x4 o1=__builtin_amdgcn_mfma_f32_16x16x32_bf16(wF[1],bhd,z4,0,0,0);  \
        f32x4 o2=__builtin_amdgcn_mfma_f32_16x16x32_bf16(wF[2],bhd,z4,0,0,0);  \
        if(lo<8){                                                              \
            float* po = out_s + ((size_t)(S)*BATCH + wb + lo)*POSE;            \
            *(float2*)(po+4*g)     = make_float2(o0[0],o0[1]);                 \
            *(float2*)(po+4*g+2)   = make_float2(o0[2],o0[3]);                 \
            *(float2*)(po+16+4*g)  = make_float2(o1[0],o1[1]);                 \
            *(float2*)(po+16+4*g+2)= make_float2(o1[2],o1[3]);                 \
            if(g==0) *(float2*)(po+32) = make_float2(o2[0],o2[1]);             \
        }                                                                      \
    }

    // ---- s = 0 (peeled: original K=64 weights, inputs = obs[31]) ----
    {
        f32x4 accc[4], accd[4];
        {
            short8 w0[4][2];
#pragma unroll
            for(int gt=0;gt<4;++gt){
                w0[gt][0]=*(const short8*)&WtU[2][gt][lo][8*g];
                w0[gt][1]=*(const short8*)&WtU[2][gt][lo][32+8*g];
            }
            short8 b0=mk_bx(xq);
            short8 b1=mk_b1(hcp0,hcp1,lo,g, f22bf(xq[4].x,xq[4].y));
            gates8(w0,b0,b1,accc);
        }
        {
            short8 w1[4][2];
#pragma unroll
            for(int gt=0;gt<4;++gt){
                w1[gt][0]=*(const short8*)&WtU[1][gt][lo][8*g];
                w1[gt][1]=*(const short8*)&WtU[1][gt][lo][32+8*g];
            }
            short8 b0=mk_bx(xq);
            short8 b1=mk_b1(hp0,hp1,lo,g, f22bf(xq[4].x,xq[4].y));
            gates8(w1,b0,b1,accd);
        }
        DEC_TAIL(0)
    }
    // ---- s = 1..14 (folded K=32 cells, all weights in VGPRs) ----
    for(int s=1;s<PREDL;++s){
        float2 pv=pbuf[wv][lo];
        f32x4 accc[4], accd[4];
        short8 b1c=mk_b1(hcp0,hcp1,lo,g, f22bf(pv.x,pv.y));
        gates4(wCp,b1c,accc);
        short8 bhd0=mk_bh(hp0,hp1,lo,g);
        gates4(wDe,bhd0,accd);
        DEC_TAIL(s)
    }
#undef DEC_TAIL
}

extern "C" void kernel_launch(void* const* d_in, const int* in_sizes, int n_in,
                              void* d_out, int out_size, void* d_ws, size_t ws_size,
                              hipStream_t stream)
{
    const float* obs  = (const float*)d_in[0];
    const float* eWih = (const float*)d_in[1];
    const float* eWhh = (const float*)d_in[2];
    const float* ebih = (const float*)d_in[3];
    const float* ebhh = (const float*)d_in[4];
    const float* dWih = (const float*)d_in[5];
    const float* dWhh = (const float*)d_in[6];
    const float* dbih = (const float*)d_in[7];
    const float* dbhh = (const float*)d_in[8];
    const float* cWih = (const float*)d_in[9];
    const float* cWhh = (const float*)d_in[10];
    const float* cbih = (const float*)d_in[11];
    const float* cbhh = (const float*)d_in[12];
    const float* fcW  = (const float*)d_in[13];
    const float* fcb  = (const float*)d_in[14];
    const float* fccW = (const float*)d_in[15];
    const float* fccb = (const float*)d_in[16];
    const float* mlpW = (const float*)d_in[17];
    const float* mlpb = (const float*)d_in[18];
    const float* embW = (const float*)d_in[19];
    const float* embb = (const float*)d_in[20];

    float* out_s  = (float*)d_out;
    float* out_cr = out_s + (size_t)PREDL*BATCH*POSE;

    dim3 grid(BATCH/32), block(256);
    hipLaunchKernelGGL(lstm_k, grid, block, 0, stream,
                       obs, eWih, eWhh, ebih, ebhh, dWih, dWhh, dbih, dbhh,
                       cWih, cWhh, cbih, cbhh, fcW, fcb, fccW, fccb,
                       mlpW, mlpb, embW, embb, out_s, out_cr);
}